// Round 4
// baseline (281.560 us; speedup 1.0000x reference)
//
#include <hip/hip_runtime.h>
#include <hip/hip_bf16.h>

#define D 128
#define H 256
#define NB 32
#define NN 128

typedef __attribute__((ext_vector_type(8))) short short8;
typedef __attribute__((ext_vector_type(8))) unsigned short ushort8;
typedef __attribute__((ext_vector_type(4))) float f32x4;
typedef __attribute__((ext_vector_type(4))) unsigned int uint4v;

__device__ __forceinline__ unsigned short to_bf16u(float f) {
  unsigned u = __builtin_bit_cast(unsigned, f);
  u = (u + 0x7fffu + ((u >> 16) & 1u)) >> 16;
  return (unsigned short)u;
}

// packed f32x2 -> bf16x2 (RNE); compiler emits v_cvt_pk_bf16_f32
__device__ __forceinline__ unsigned cvt_pk(float lo, float hi) {
  union { __hip_bfloat162 h; unsigned u; } c;
  c.h = __float22bfloat162_rn(make_float2(lo, hi));
  return c.u;
}

// ---------------- Kernel 1: LayerNorm*mask + projections through mw1 ----------------
// Outputs xi_p [B*N,H] f32 and xjb [B*N,H] bf16.
__global__ __launch_bounds__(256) void k_ln_proj(
    const float* __restrict__ nodes, const float* __restrict__ node_mask,
    const float* __restrict__ ln_g, const float* __restrict__ ln_b,
    const float* __restrict__ mw1,
    float* __restrict__ xi_p, unsigned short* __restrict__ xjb) {
  const int row0 = blockIdx.x * 8;
  const int tid = threadIdx.x;
  const int r = tid >> 5;            // 0..7 (row within block)
  const int c4 = (tid & 31) << 2;    // 0,4,...,124
  __shared__ float xs[8][128];

  float4 v = *(const float4*)(nodes + (size_t)(row0 + r) * D + c4);
  float s1 = v.x + v.y + v.z + v.w;
  float s2 = v.x * v.x + v.y * v.y + v.z * v.z + v.w * v.w;
#pragma unroll
  for (int off = 1; off < 32; off <<= 1) {
    s1 += __shfl_xor(s1, off);
    s2 += __shfl_xor(s2, off);
  }
  float mu = s1 * (1.0f / 128.0f);
  float var = s2 * (1.0f / 128.0f) - mu * mu;
  float rsig = rsqrtf(var + 1e-5f);
  float m = node_mask[row0 + r];
  float4 g4 = *(const float4*)(ln_g + c4);
  float4 b4 = *(const float4*)(ln_b + c4);
  float4 x4;
  x4.x = ((v.x - mu) * rsig * g4.x + b4.x) * m;
  x4.y = ((v.y - mu) * rsig * g4.y + b4.y) * m;
  x4.z = ((v.z - mu) * rsig * g4.z + b4.z) * m;
  x4.w = ((v.w - mu) * rsig * g4.w + b4.w) * m;
  *(float4*)(&xs[r][c4]) = x4;
  __syncthreads();

  float ai[8], aj[8];
#pragma unroll
  for (int rr = 0; rr < 8; ++rr) { ai[rr] = 0.f; aj[rr] = 0.f; }
#pragma unroll 4
  for (int d = 0; d < 128; ++d) {
    float wi = mw1[d * H + tid];
    float wj = mw1[(D + d) * H + tid];
#pragma unroll
    for (int rr = 0; rr < 8; ++rr) {
      float xv = xs[rr][d];
      ai[rr] = fmaf(xv, wi, ai[rr]);
      aj[rr] = fmaf(xv, wj, aj[rr]);
    }
  }
#pragma unroll
  for (int rr = 0; rr < 8; ++rr) {
    xi_p[(size_t)(row0 + rr) * H + tid] = ai[rr];
    xjb[(size_t)(row0 + rr) * H + tid] = to_bf16u(aj[rr]);
  }
}

// ---------------- Repack mw2 [H][D] f32 -> bf16 MFMA B-fragment order ----------------
// frag tile (ks,nt): lane l, elem e holds mw2[ks*32 + (l>>4)*8 + e][nt*16 + (l&15)]
__global__ void k_repack(const float* __restrict__ mw2, short* __restrict__ bw2) {
  const int t = blockIdx.x * 64 + threadIdx.x;  // 0..4095
  const int lane = t & 63;
  const int tile = t >> 6;   // ks*8+nt, 0..63
  const int ks = tile >> 3, nt = tile & 7;
#pragma unroll
  for (int e = 0; e < 8; ++e) {
    int k = ks * 32 + ((lane >> 4) << 3) + e;
    int d = nt * 16 + (lane & 15);
    bw2[(size_t)t * 8 + e] = (short)to_bf16u(mw2[k * D + d]);
  }
}

// ---------------- Kernel 2: msgs GEMM + mask + sum over j -> agg ----------------
// Block: 8 waves (512 thr), 4 i's. Wave w: i = i0 + (w>>1), j-slab = (w&1)*64,
// TM=64 rows, N=128, K=256. B staged once in LDS (64 KB). xjb loads software-
// pipelined one ks-step ahead.
__global__ __launch_bounds__(512, 4) void k_msgs(
    const float* __restrict__ xi_p, const unsigned short* __restrict__ xjb,
    const short* __restrict__ bw2g, const float* __restrict__ mb1,
    const float* __restrict__ mb2, const float* __restrict__ node_mask,
    float* __restrict__ agg) {
  const int b = blockIdx.y;
  const int i0 = blockIdx.x * 4;
  const int tid = threadIdx.x;           // 0..511
  const int w = tid >> 6, l = tid & 63;  // 8 waves
  const int iw = w >> 1;                 // 0..3: which i
  const int jbase = (w & 1) * 64;        // which j-slab
  const int lg = l >> 4, l15 = l & 15;

  __shared__ short bw2s[32768];          // 64 KB B fragments
  __shared__ float cs[4][256];           // xi_p row + mb1, per i
  __shared__ float mb2s[128], maskS[128];
  __shared__ float waveAgg[8][128];

  {
    const uint4v* src = (const uint4v*)bw2g;
    uint4v* dst = (uint4v*)bw2s;
#pragma unroll
    for (int c = 0; c < 8; ++c) dst[c * 512 + tid] = src[c * 512 + tid];
  }
#pragma unroll
  for (int c = 0; c < 2; ++c) {
    int idx = c * 512 + tid;             // 0..1023
    int ii = idx >> 8, k = idx & 255;
    cs[ii][k] = xi_p[(size_t)(b * NN + i0 + ii) * H + k] + mb1[k];
  }
  if (tid < 128) { mb2s[tid] = mb2[tid]; maskS[tid] = node_mask[b * NN + tid]; }
  __syncthreads();

  const unsigned short* xrow[4];
#pragma unroll
  for (int mf = 0; mf < 4; ++mf)
    xrow[mf] = xjb + (size_t)(b * NN + jbase + mf * 16 + l15) * H;

  f32x4 acc[4][8];
#pragma unroll
  for (int mf = 0; mf < 4; ++mf)
#pragma unroll
    for (int nt = 0; nt < 8; ++nt)
      acc[mf][nt] = (f32x4){0.f, 0.f, 0.f, 0.f};

  const short8* bfrag = (const short8*)bw2s;

  ushort8 xv[4];
#pragma unroll
  for (int mf = 0; mf < 4; ++mf)
    xv[mf] = *(const ushort8*)(xrow[mf] + lg * 8);

#pragma unroll
  for (int ks = 0; ks < 8; ++ks) {
    const int kb = ks * 32 + lg * 8;
    ushort8 xn[4];
    if (ks < 7) {
#pragma unroll
      for (int mf = 0; mf < 4; ++mf)
        xn[mf] = *(const ushort8*)(xrow[mf] + kb + 32);
    }
    float cc[8];
    {
      float4 c0 = *(const float4*)(&cs[iw][kb]);
      float4 c1 = *(const float4*)(&cs[iw][kb + 4]);
      cc[0] = c0.x; cc[1] = c0.y; cc[2] = c0.z; cc[3] = c0.w;
      cc[4] = c1.x; cc[5] = c1.y; cc[6] = c1.z; cc[7] = c1.w;
    }
    short8 af[4];
#pragma unroll
    for (int mf = 0; mf < 4; ++mf) {
      float hv[8];
#pragma unroll
      for (int e = 0; e < 8; ++e) {
        float xf = __builtin_bit_cast(float, ((unsigned)xv[mf][e]) << 16);
        hv[e] = fmaxf(xf + cc[e], 0.f);
      }
      uint4v u;
#pragma unroll
      for (int p = 0; p < 4; ++p) u[p] = cvt_pk(hv[2 * p], hv[2 * p + 1]);
      af[mf] = __builtin_bit_cast(short8, u);
    }
#pragma unroll
    for (int nt = 0; nt < 8; ++nt) {
      short8 bf = bfrag[(ks * 8 + nt) * 64 + l];
#pragma unroll
      for (int mf = 0; mf < 4; ++mf)
        acc[mf][nt] = __builtin_amdgcn_mfma_f32_16x16x32_bf16(af[mf], bf, acc[mf][nt], 0, 0, 0);
    }
    if (ks < 7) {
#pragma unroll
      for (int mf = 0; mf < 4; ++mf) xv[mf] = xn[mf];
    }
  }

  // Epilogue: relu(acc+mb2)*mask_j, column-sum over the wave's 64 rows.
#pragma unroll
  for (int nt = 0; nt < 8; ++nt) {
    const float bias = mb2s[nt * 16 + l15];
    float s = 0.f;
#pragma unroll
    for (int mf = 0; mf < 4; ++mf) {
      const int jb = jbase + mf * 16 + lg * 4;
#pragma unroll
      for (int r = 0; r < 4; ++r)
        s = fmaf(fmaxf(acc[mf][nt][r] + bias, 0.f), maskS[jb + r], s);
    }
    s += __shfl_xor(s, 16);
    s += __shfl_xor(s, 32);
    if (l < 16) waveAgg[w][nt * 16 + l15] = s;
  }
  __syncthreads();
  {
    const int ii = tid >> 7, col = tid & 127;  // 4 i's x 128 cols
    agg[(size_t)(b * NN + i0 + ii) * D + col] =
        waveAgg[ii * 2][col] + waveAgg[ii * 2 + 1][col];
  }
}

// ---------------- Kernel 3: update MLP + residual + mask ----------------
__global__ __launch_bounds__(256) void k_upd(
    const float* __restrict__ nodes, const float* __restrict__ agg,
    const float* __restrict__ uw1, const float* __restrict__ ub1,
    const float* __restrict__ uw2, const float* __restrict__ ub2,
    const float* __restrict__ node_mask, float* __restrict__ out) {
  const int row0 = blockIdx.x * 8;
  const int tid = threadIdx.x;
  __shared__ float ns[8][128];
  __shared__ float as2[8][128];
  __shared__ float us[8][256];
  {
    const int r = tid >> 5;
    const int c4 = (tid & 31) << 2;
    *(float4*)(&ns[r][c4]) = *(const float4*)(nodes + (size_t)(row0 + r) * D + c4);
    *(float4*)(&as2[r][c4]) = *(const float4*)(agg + (size_t)(row0 + r) * D + c4);
  }
  __syncthreads();

  float acc[8];
  {
    float bias = ub1[tid];
#pragma unroll
    for (int rr = 0; rr < 8; ++rr) acc[rr] = bias;
  }
#pragma unroll 4
  for (int d = 0; d < 128; ++d) {
    float wa = uw1[d * H + tid];
    float wb = uw1[(D + d) * H + tid];
#pragma unroll
    for (int rr = 0; rr < 8; ++rr) {
      acc[rr] = fmaf(ns[rr][d], wa, acc[rr]);
      acc[rr] = fmaf(as2[rr][d], wb, acc[rr]);
    }
  }
#pragma unroll
  for (int rr = 0; rr < 8; ++rr) us[rr][tid] = fmaxf(acc[rr], 0.f);
  __syncthreads();

  const int dcol = tid & 127;
  const int rbase = tid >> 7;  // 0 or 1
  float o[4] = {0.f, 0.f, 0.f, 0.f};
#pragma unroll 4
  for (int h = 0; h < 256; ++h) {
    float wv = uw2[h * D + dcol];
#pragma unroll
    for (int p = 0; p < 4; ++p) o[p] = fmaf(us[rbase + 2 * p][h], wv, o[p]);
  }
  const float ub2v = ub2[dcol];
#pragma unroll
  for (int p = 0; p < 4; ++p) {
    const int rr = rbase + 2 * p;
    out[(size_t)(row0 + rr) * D + dcol] =
        (ns[rr][dcol] + o[p] + ub2v) * node_mask[row0 + rr];
  }
}

extern "C" void kernel_launch(void* const* d_in, const int* in_sizes, int n_in,
                              void* d_out, int out_size, void* d_ws, size_t ws_size,
                              hipStream_t stream) {
  (void)in_sizes; (void)n_in; (void)out_size; (void)ws_size;
  const float* nodes     = (const float*)d_in[0];
  const float* node_mask = (const float*)d_in[1];
  const float* ln_g      = (const float*)d_in[2];
  const float* ln_b      = (const float*)d_in[3];
  const float* mw1       = (const float*)d_in[4];
  const float* mb1       = (const float*)d_in[5];
  const float* mw2       = (const float*)d_in[6];
  const float* mb2       = (const float*)d_in[7];
  const float* uw1       = (const float*)d_in[8];
  const float* ub1       = (const float*)d_in[9];
  const float* uw2       = (const float*)d_in[10];
  const float* ub2       = (const float*)d_in[11];
  float* out = (float*)d_out;

  char* ws = (char*)d_ws;
  float*          xi_p = (float*)(ws);                              // 4 MB
  unsigned short* xjb  = (unsigned short*)(ws + ((size_t)4 << 20)); // 2 MB
  float*          agg  = (float*)(ws + ((size_t)6 << 20));          // 2 MB
  short*          bw2  = (short*)(ws + ((size_t)8 << 20));          // 64 KB

  k_ln_proj<<<512, 256, 0, stream>>>(nodes, node_mask, ln_g, ln_b, mw1, xi_p, xjb);
  k_repack<<<64, 64, 0, stream>>>(mw2, bw2);
  k_msgs<<<dim3(NN / 4, NB), 512, 0, stream>>>(xi_p, xjb, bw2, mb1, mb2, node_mask, agg);
  k_upd<<<512, 256, 0, stream>>>(nodes, agg, uw1, ub1, uw2, ub2, node_mask, out);
}

// Round 5
// 93.110 us; speedup vs baseline: 3.0239x; 3.0239x over previous
//
#include <hip/hip_runtime.h>
#include <hip/hip_bf16.h>

#define D 128
#define H 256
#define NB 32
#define NN 128

typedef __attribute__((ext_vector_type(8))) short short8;
typedef __attribute__((ext_vector_type(8))) unsigned short ushort8;
typedef __attribute__((ext_vector_type(4))) float f32x4;
typedef __attribute__((ext_vector_type(4))) unsigned int uint4v;

__device__ __forceinline__ unsigned short to_bf16u(float f) {
  unsigned u = __builtin_bit_cast(unsigned, f);
  u = (u + 0x7fffu + ((u >> 16) & 1u)) >> 16;
  return (unsigned short)u;
}

// packed f32x2 -> bf16x2 (RNE); compiler emits v_cvt_pk_bf16_f32
__device__ __forceinline__ unsigned cvt_pk(float lo, float hi) {
  union { __hip_bfloat162 h; unsigned u; } c;
  c.h = __float22bfloat162_rn(make_float2(lo, hi));
  return c.u;
}

// ---------------- Kernel 1: LayerNorm*mask + projections through mw1 ----------------
// Outputs xi_p [B*N,H] f32 and xjb [B*N,H] bf16.
__global__ __launch_bounds__(256) void k_ln_proj(
    const float* __restrict__ nodes, const float* __restrict__ node_mask,
    const float* __restrict__ ln_g, const float* __restrict__ ln_b,
    const float* __restrict__ mw1,
    float* __restrict__ xi_p, unsigned short* __restrict__ xjb) {
  const int row0 = blockIdx.x * 8;
  const int tid = threadIdx.x;
  const int r = tid >> 5;            // 0..7 (row within block)
  const int c4 = (tid & 31) << 2;    // 0,4,...,124
  __shared__ float xs[8][128];

  float4 v = *(const float4*)(nodes + (size_t)(row0 + r) * D + c4);
  float s1 = v.x + v.y + v.z + v.w;
  float s2 = v.x * v.x + v.y * v.y + v.z * v.z + v.w * v.w;
#pragma unroll
  for (int off = 1; off < 32; off <<= 1) {
    s1 += __shfl_xor(s1, off);
    s2 += __shfl_xor(s2, off);
  }
  float mu = s1 * (1.0f / 128.0f);
  float var = s2 * (1.0f / 128.0f) - mu * mu;
  float rsig = rsqrtf(var + 1e-5f);
  float m = node_mask[row0 + r];
  float4 g4 = *(const float4*)(ln_g + c4);
  float4 b4 = *(const float4*)(ln_b + c4);
  float4 x4;
  x4.x = ((v.x - mu) * rsig * g4.x + b4.x) * m;
  x4.y = ((v.y - mu) * rsig * g4.y + b4.y) * m;
  x4.z = ((v.z - mu) * rsig * g4.z + b4.z) * m;
  x4.w = ((v.w - mu) * rsig * g4.w + b4.w) * m;
  *(float4*)(&xs[r][c4]) = x4;
  __syncthreads();

  float ai[8], aj[8];
#pragma unroll
  for (int rr = 0; rr < 8; ++rr) { ai[rr] = 0.f; aj[rr] = 0.f; }
#pragma unroll 4
  for (int d = 0; d < 128; ++d) {
    float wi = mw1[d * H + tid];
    float wj = mw1[(D + d) * H + tid];
#pragma unroll
    for (int rr = 0; rr < 8; ++rr) {
      float xv = xs[rr][d];
      ai[rr] = fmaf(xv, wi, ai[rr]);
      aj[rr] = fmaf(xv, wj, aj[rr]);
    }
  }
#pragma unroll
  for (int rr = 0; rr < 8; ++rr) {
    xi_p[(size_t)(row0 + rr) * H + tid] = ai[rr];
    xjb[(size_t)(row0 + rr) * H + tid] = to_bf16u(aj[rr]);
  }
}

// ---------------- Repack mw2 [H][D] f32 -> bf16 MFMA B-fragment order ----------------
// frag tile (ks,nt): lane l, elem e holds mw2[ks*32 + (l>>4)*8 + e][nt*16 + (l&15)]
__global__ void k_repack(const float* __restrict__ mw2, short* __restrict__ bw2) {
  const int t = blockIdx.x * 64 + threadIdx.x;  // 0..4095
  const int lane = t & 63;
  const int tile = t >> 6;   // ks*8+nt, 0..63
  const int ks = tile >> 3, nt = tile & 7;
#pragma unroll
  for (int e = 0; e < 8; ++e) {
    int k = ks * 32 + ((lane >> 4) << 3) + e;
    int d = nt * 16 + (lane & 15);
    bw2[(size_t)t * 8 + e] = (short)to_bf16u(mw2[k * D + d]);
  }
}

// ---------------- Kernel 2: msgs GEMM + mask + sum over j -> agg ----------------
// Block: 8 waves (512 thr), 2 i's. Wave w: i = i0 + (w>>2), j-slab = (w&3)*32,
// TM=32 rows, N=128, K=256. B staged once in LDS (64 KB). TM=32 keeps per-wave
// regs ~110 so __launch_bounds__(512,4) holds 4 waves/SIMD WITHOUT spills
// (R4 lesson: TM=64 + cap 128 => scratch spills, FETCH 395MB, 4x regression).
__global__ __launch_bounds__(512, 4) void k_msgs(
    const float* __restrict__ xi_p, const unsigned short* __restrict__ xjb,
    const short* __restrict__ bw2g, const float* __restrict__ mb1,
    const float* __restrict__ mb2, const float* __restrict__ node_mask,
    float* __restrict__ agg) {
  const int b = blockIdx.y;
  const int i0 = blockIdx.x * 2;
  const int tid = threadIdx.x;           // 0..511
  const int w = tid >> 6, l = tid & 63;  // 8 waves
  const int iw = w >> 2;                 // 0..1: which i
  const int jbase = (w & 3) * 32;        // which 32-row j-slab
  const int lg = l >> 4, l15 = l & 15;

  __shared__ short bw2s[32768];          // 64 KB B fragments
  __shared__ float cs[2][256];           // xi_p row + mb1, per i
  __shared__ float mb2s[128], maskS[128];
  __shared__ float waveAgg[8][128];

  {
    const uint4v* src = (const uint4v*)bw2g;
    uint4v* dst = (uint4v*)bw2s;
#pragma unroll
    for (int c = 0; c < 8; ++c) dst[c * 512 + tid] = src[c * 512 + tid];
  }
  {
    int ii = tid >> 8, k = tid & 255;    // 512 threads = 2 x 256
    cs[ii][k] = xi_p[(size_t)(b * NN + i0 + ii) * H + k] + mb1[k];
  }
  if (tid < 128) { mb2s[tid] = mb2[tid]; maskS[tid] = node_mask[b * NN + tid]; }
  __syncthreads();

  const unsigned short* xrow[2];
#pragma unroll
  for (int mf = 0; mf < 2; ++mf)
    xrow[mf] = xjb + (size_t)(b * NN + jbase + mf * 16 + l15) * H;

  f32x4 acc[2][8];
#pragma unroll
  for (int mf = 0; mf < 2; ++mf)
#pragma unroll
    for (int nt = 0; nt < 8; ++nt)
      acc[mf][nt] = (f32x4){0.f, 0.f, 0.f, 0.f};

  const short8* bfrag = (const short8*)bw2s;

#pragma unroll
  for (int ks = 0; ks < 8; ++ks) {
    const int kb = ks * 32 + lg * 8;
    ushort8 xv[2];
#pragma unroll
    for (int mf = 0; mf < 2; ++mf)
      xv[mf] = *(const ushort8*)(xrow[mf] + kb);
    float cc[8];
    {
      float4 c0 = *(const float4*)(&cs[iw][kb]);
      float4 c1 = *(const float4*)(&cs[iw][kb + 4]);
      cc[0] = c0.x; cc[1] = c0.y; cc[2] = c0.z; cc[3] = c0.w;
      cc[4] = c1.x; cc[5] = c1.y; cc[6] = c1.z; cc[7] = c1.w;
    }
    short8 af[2];
#pragma unroll
    for (int mf = 0; mf < 2; ++mf) {
      float hv[8];
#pragma unroll
      for (int e = 0; e < 8; ++e) {
        float xf = __builtin_bit_cast(float, ((unsigned)xv[mf][e]) << 16);
        hv[e] = fmaxf(xf + cc[e], 0.f);
      }
      uint4v u;
#pragma unroll
      for (int p = 0; p < 4; ++p) u[p] = cvt_pk(hv[2 * p], hv[2 * p + 1]);
      af[mf] = __builtin_bit_cast(short8, u);
    }
#pragma unroll
    for (int nt = 0; nt < 8; ++nt) {
      short8 bf = bfrag[(ks * 8 + nt) * 64 + l];
#pragma unroll
      for (int mf = 0; mf < 2; ++mf)
        acc[mf][nt] = __builtin_amdgcn_mfma_f32_16x16x32_bf16(af[mf], bf, acc[mf][nt], 0, 0, 0);
    }
  }

  // Epilogue: relu(acc+mb2)*mask_j, column-sum over the wave's 32 rows.
#pragma unroll
  for (int nt = 0; nt < 8; ++nt) {
    const float bias = mb2s[nt * 16 + l15];
    float s = 0.f;
#pragma unroll
    for (int mf = 0; mf < 2; ++mf) {
      const int jb = jbase + mf * 16 + lg * 4;
#pragma unroll
      for (int r = 0; r < 4; ++r)
        s = fmaf(fmaxf(acc[mf][nt][r] + bias, 0.f), maskS[jb + r], s);
    }
    s += __shfl_xor(s, 16);
    s += __shfl_xor(s, 32);
    if (l < 16) waveAgg[w][nt * 16 + l15] = s;
  }
  __syncthreads();
  if (tid < 256) {
    const int ii = tid >> 7, col = tid & 127;  // 2 i's x 128 cols
    agg[(size_t)(b * NN + i0 + ii) * D + col] =
        waveAgg[ii * 4][col] + waveAgg[ii * 4 + 1][col] +
        waveAgg[ii * 4 + 2][col] + waveAgg[ii * 4 + 3][col];
  }
}

// ---------------- Kernel 3: update MLP + residual + mask ----------------
__global__ __launch_bounds__(256) void k_upd(
    const float* __restrict__ nodes, const float* __restrict__ agg,
    const float* __restrict__ uw1, const float* __restrict__ ub1,
    const float* __restrict__ uw2, const float* __restrict__ ub2,
    const float* __restrict__ node_mask, float* __restrict__ out) {
  const int row0 = blockIdx.x * 8;
  const int tid = threadIdx.x;
  __shared__ float ns[8][128];
  __shared__ float as2[8][128];
  __shared__ float us[8][256];
  {
    const int r = tid >> 5;
    const int c4 = (tid & 31) << 2;
    *(float4*)(&ns[r][c4]) = *(const float4*)(nodes + (size_t)(row0 + r) * D + c4);
    *(float4*)(&as2[r][c4]) = *(const float4*)(agg + (size_t)(row0 + r) * D + c4);
  }
  __syncthreads();

  float acc[8];
  {
    float bias = ub1[tid];
#pragma unroll
    for (int rr = 0; rr < 8; ++rr) acc[rr] = bias;
  }
#pragma unroll 4
  for (int d = 0; d < 128; ++d) {
    float wa = uw1[d * H + tid];
    float wb = uw1[(D + d) * H + tid];
#pragma unroll
    for (int rr = 0; rr < 8; ++rr) {
      acc[rr] = fmaf(ns[rr][d], wa, acc[rr]);
      acc[rr] = fmaf(as2[rr][d], wb, acc[rr]);
    }
  }
#pragma unroll
  for (int rr = 0; rr < 8; ++rr) us[rr][tid] = fmaxf(acc[rr], 0.f);
  __syncthreads();

  const int dcol = tid & 127;
  const int rbase = tid >> 7;  // 0 or 1
  float o[4] = {0.f, 0.f, 0.f, 0.f};
#pragma unroll 4
  for (int h = 0; h < 256; ++h) {
    float wv = uw2[h * D + dcol];
#pragma unroll
    for (int p = 0; p < 4; ++p) o[p] = fmaf(us[rbase + 2 * p][h], wv, o[p]);
  }
  const float ub2v = ub2[dcol];
#pragma unroll
  for (int p = 0; p < 4; ++p) {
    const int rr = rbase + 2 * p;
    out[(size_t)(row0 + rr) * D + dcol] =
        (ns[rr][dcol] + o[p] + ub2v) * node_mask[row0 + rr];
  }
}

extern "C" void kernel_launch(void* const* d_in, const int* in_sizes, int n_in,
                              void* d_out, int out_size, void* d_ws, size_t ws_size,
                              hipStream_t stream) {
  (void)in_sizes; (void)n_in; (void)out_size; (void)ws_size;
  const float* nodes     = (const float*)d_in[0];
  const float* node_mask = (const float*)d_in[1];
  const float* ln_g      = (const float*)d_in[2];
  const float* ln_b      = (const float*)d_in[3];
  const float* mw1       = (const float*)d_in[4];
  const float* mb1       = (const float*)d_in[5];
  const float* mw2       = (const float*)d_in[6];
  const float* mb2       = (const float*)d_in[7];
  const float* uw1       = (const float*)d_in[8];
  const float* ub1       = (const float*)d_in[9];
  const float* uw2       = (const float*)d_in[10];
  const float* ub2       = (const float*)d_in[11];
  float* out = (float*)d_out;

  char* ws = (char*)d_ws;
  float*          xi_p = (float*)(ws);                              // 4 MB
  unsigned short* xjb  = (unsigned short*)(ws + ((size_t)4 << 20)); // 2 MB
  float*          agg  = (float*)(ws + ((size_t)6 << 20));          // 2 MB
  short*          bw2  = (short*)(ws + ((size_t)8 << 20));          // 64 KB

  k_ln_proj<<<512, 256, 0, stream>>>(nodes, node_mask, ln_g, ln_b, mw1, xi_p, xjb);
  k_repack<<<64, 64, 0, stream>>>(mw2, bw2);
  k_msgs<<<dim3(NN / 2, NB), 512, 0, stream>>>(xi_p, xjb, bw2, mb1, mb2, node_mask, agg);
  k_upd<<<512, 256, 0, stream>>>(nodes, agg, uw1, ub1, uw2, ub2, node_mask, out);
}